// Round 11
// baseline (241.598 us; speedup 1.0000x reference)
//
#include <hip/hip_runtime.h>

typedef unsigned short u16;
typedef __bf16 bf16x8 __attribute__((ext_vector_type(8)));
typedef __bf16 bf16x4 __attribute__((ext_vector_type(4)));
typedef float f32x4 __attribute__((ext_vector_type(4)));

__device__ __forceinline__ u16 f2bf(float f) {
    union { float f; unsigned int i; } v;
    v.f = f;
    unsigned int u = v.i;
    return (u16)((u + 0x7fffu + ((u >> 16) & 1u)) >> 16);  // RNE
}

// async global->LDS DMA, 16B/lane; LDS dest = wave-uniform base + lane*16
__device__ __forceinline__ void dma16(const void* g, void* l) {
    __builtin_amdgcn_global_load_lds(
        (__attribute__((address_space(1))) void*)g,
        (__attribute__((address_space(3))) void*)l, 16, 0, 0);
}

#define SC2 0.18033688f  // (1/sqrt(64)) * log2(e), folded into Q at projection

// Swizzle: buffers staged into [row][64] LDS tiles store (row, col) at
// col ^ (key<<3). Q-half of QKg / Vgt / ATT / xbf / WT use key = row&7.
// K-half of QKg uses key = (row>>2)&7 so sigma-staged rows compensate to l16&7.

// ---- fused transpose+cvt+swizzle: 4x W[k][n] f32 -> WT[n][k^((n&7)<<3)] bf16 ----
__global__ __launch_bounds__(256) void cvt_w4(
    const float* __restrict__ W0, const float* __restrict__ W1,
    const float* __restrict__ W2, const float* __restrict__ W3,
    u16* __restrict__ out) {
    __shared__ u16 t[32][33];
    int z = blockIdx.z;
    const float* in = (z == 0) ? W0 : (z == 1) ? W1 : (z == 2) ? W2 : W3;
    u16* o = out + (size_t)z * 1048576;
    int bx = blockIdx.x * 32, by = blockIdx.y * 32;
    int tx = threadIdx.x & 31, ty = threadIdx.x >> 5;
#pragma unroll
    for (int i = 0; i < 32; i += 8)
        t[ty + i][tx] = f2bf(in[(size_t)(by + ty + i) * 1024 + bx + tx]);
    __syncthreads();
#pragma unroll
    for (int i = 0; i < 32; i += 8) {
        int n = bx + ty + i, k = by + tx;
        o[(size_t)n * 1024 + (k ^ ((n & 7) << 3))] = t[tx][ty + i];
    }
}

// ---- f32 -> bf16 + swizzle: x[s][k] -> xbf[s][k^((s&7)<<3)] ----
__global__ __launch_bounds__(256) void cvt_x(const float* __restrict__ in,
                                             u16* __restrict__ out) {
    int i = blockIdx.x * 256 + threadIdx.x;
    int s = i >> 8, k = (i & 255) * 4;
    float4 f = reinterpret_cast<const float4*>(in)[i];
    ushort4 h;
    h.x = f2bf(f.x); h.y = f2bf(f.y); h.z = f2bf(f.z); h.w = f2bf(f.w);
    *reinterpret_cast<ushort4*>(&out[(size_t)s * 1024 + (k ^ ((s & 7) << 3))]) = h;
}

// ---- QKV GEMM: seg 0/1 -> QKg[b][s][2048] (q|k), seg 2 -> Vgt[b*1024+v][s] ----
// Q cols keyed (s&7) and PRE-SCALED by SC2; K cols keyed ((s>>2)&7); Vgt (v&7).
__global__ __launch_bounds__(256) void gemm_qkv(
    const u16* __restrict__ xbf, const u16* __restrict__ wt,
    const float* __restrict__ bq, const float* __restrict__ bk,
    const float* __restrict__ bv,
    u16* __restrict__ qkg, u16* __restrict__ vgt) {
    __shared__ __align__(16) u16 As[128 * 64];
    __shared__ __align__(16) u16 Bs[128 * 64];

    int tid = threadIdx.x;
    int m0 = blockIdx.y * 128, n0 = blockIdx.x * 128;
    int wave = tid >> 6, lane = tid & 63;
    int wm = (wave >> 1) * 64, wn = (wave & 1) * 64;
    int l16 = lane & 15, quad = lane >> 4;
    int sl = l16 & 7;

    int seg = n0 >> 10;
    int n0r = n0 & 1023;
    const u16* WT = wt + (size_t)seg * 1048576;
    bool swp = (seg == 2);

    f32x4 acc[4][4];
#pragma unroll
    for (int mi = 0; mi < 4; mi++)
#pragma unroll
        for (int ni = 0; ni < 4; ni++) acc[mi][ni] = (f32x4){0.f, 0.f, 0.f, 0.f};

    int rsub = lane >> 3, c16 = (lane & 7) * 8;
    for (int k0 = 0; k0 < 1024; k0 += 64) {
#pragma unroll
        for (int i = 0; i < 4; i++) {
            int row = wave * 32 + i * 8 + rsub;
            dma16(&xbf[(size_t)(m0 + row) * 1024 + k0 + c16], &As[wave * 2048 + i * 512]);
            dma16(&WT[(size_t)(n0r + row) * 1024 + k0 + c16], &Bs[wave * 2048 + i * 512]);
        }
        __syncthreads();
        const u16* Am = swp ? Bs : As;
        const u16* Bn = swp ? As : Bs;
#pragma unroll
        for (int kk = 0; kk < 64; kk += 32) {
            int co = ((((kk >> 3) + quad) ^ sl) << 3);
            bf16x8 af[4], bf[4];
#pragma unroll
            for (int mi = 0; mi < 4; mi++)
                af[mi] = *reinterpret_cast<const bf16x8*>(
                    &Am[(wm + mi * 16 + l16) * 64 + co]);
#pragma unroll
            for (int ni = 0; ni < 4; ni++)
                bf[ni] = *reinterpret_cast<const bf16x8*>(
                    &Bn[(wn + ni * 16 + l16) * 64 + co]);
#pragma unroll
            for (int mi = 0; mi < 4; mi++)
#pragma unroll
                for (int ni = 0; ni < 4; ni++)
                    acc[mi][ni] = __builtin_amdgcn_mfma_f32_16x16x32_bf16(
                        af[mi], bf[ni], acc[mi][ni], 0, 0, 0);
        }
        __syncthreads();
    }

    if (!swp) {
        float scale = (seg == 0) ? SC2 : 1.0f;  // fold softmax scale into Q
#pragma unroll
        for (int ni = 0; ni < 4; ni++) {
            int n = n0 + wn + ni * 16 + l16;  // 0..2047
            float bb = (n < 1024) ? bq[n] : bk[n - 1024];
#pragma unroll
            for (int mi = 0; mi < 4; mi++)
#pragma unroll
                for (int r = 0; r < 4; r++) {
                    int s = m0 + wm + mi * 16 + quad * 4 + r;
                    int key = (seg == 0) ? (s & 7) : ((s >> 2) & 7);
                    int col = n ^ (key << 3);
                    qkg[(size_t)(s >> 11) * 4194304 + (size_t)(s & 2047) * 2048 + col] =
                        f2bf((acc[mi][ni][r] + bb) * scale);
                }
        }
    } else {
#pragma unroll
        for (int mi = 0; mi < 4; mi++)
#pragma unroll
            for (int r = 0; r < 4; r++) {
                int v = n0r + wm + mi * 16 + quad * 4 + r;  // 0..1023
                float bb = bv[v];
#pragma unroll
                for (int ni = 0; ni < 4; ni++) {
                    int s = m0 + wn + ni * 16 + l16;
                    int scol = (s & 2047) ^ ((v & 7) << 3);
                    vgt[(size_t)((s >> 11) * 1024 + v) * 2048 + scol] =
                        f2bf(acc[mi][ni][r] + bb);
                }
            }
    }
}

// ---- flash attention: 64-row q-tiles, fixed-C softmax, sigma keys, and a
// single-barrier double-buffered K/V pipeline (prefetch issued post-barrier so
// the compiler's vmcnt(0)-before-s_barrier drains a load that overlapped a full
// kt of compute). Output overwrites this block's own Q-tile in QKg.
__global__ __launch_bounds__(256) void attention_kern(
    u16* __restrict__ qkg, const u16* __restrict__ vgt) {
    __shared__ __align__(16) u16 Qs[64 * 64];
    __shared__ __align__(16) u16 Ks[2][64 * 64];  // sigma-permuted key rows
    __shared__ __align__(16) u16 Vt[2][64 * 64];  // [hd][key]
    __shared__ __align__(16) u16 Ps[64 * 64];     // [qrow][key]

    int tid = threadIdx.x;
    int qt = blockIdx.x, h = blockIdx.y, b = blockIdx.z;
    int wave = tid >> 6, lane = tid & 63;
    int l16 = lane & 15, quad = lane >> 4;
    int rsub = lane >> 3, c16 = (lane & 7) * 8;
    int sl = l16 & 7;

    u16* qb = qkg + (size_t)b * 4194304 + (size_t)(qt * 64) * 2048 + h * 64;
    const u16* kb = qkg + (size_t)b * 4194304 + 1024 + h * 64;
    const u16* vb = vgt + (size_t)(b * 1024 + h * 64) * 2048;

#pragma unroll
    for (int i = 0; i < 2; i++) {
        int row = wave * 16 + i * 8 + rsub;
        dma16(&qb[(size_t)row * 2048 + c16], &Qs[wave * 1024 + i * 512]);
    }

    // prologue: stage kt=0 into buffer 0
    {
        const u16* ktb = kb;
        const u16* vtb = vb;
#pragma unroll
        for (int i = 0; i < 2; i++) {
            int gk = 32 * i + 4 * rsub + wave;
            dma16(&ktb[(size_t)gk * 2048 + c16], &Ks[0][wave * 1024 + i * 512]);
            int rv = wave * 16 + i * 8 + rsub;
            dma16(&vtb[(size_t)rv * 2048 + c16], &Vt[0][wave * 1024 + i * 512]);
        }
    }

    float lp[4];
    f32x4 o[4];
#pragma unroll
    for (int r = 0; r < 4; r++) lp[r] = 0.f;
#pragma unroll
    for (int ni = 0; ni < 4; ni++) o[ni] = (f32x4){0.f, 0.f, 0.f, 0.f};

    for (int kt = 0; kt < 32; kt++) {
        __syncthreads();  // drains DMA(kt) (issued a full iteration ago)

        if (kt < 31) {    // prefetch kt+1 into the other buffer
            int nb = (kt + 1) & 1;
            const u16* ktb = kb + (size_t)((kt + 1) * 64) * 2048;
            const u16* vtb = vb + (kt + 1) * 64;
#pragma unroll
            for (int i = 0; i < 2; i++) {
                int gk = 32 * i + 4 * rsub + wave;
                dma16(&ktb[(size_t)gk * 2048 + c16], &Ks[nb][wave * 1024 + i * 512]);
                int rv = wave * 16 + i * 8 + rsub;
                dma16(&vtb[(size_t)rv * 2048 + c16], &Vt[nb][wave * 1024 + i * 512]);
            }
        }
        int cb = kt & 1;

        // S = Q K^T (Q pre-scaled by SC2; all frag reads use key l16&7)
        f32x4 s[4];
#pragma unroll
        for (int ni = 0; ni < 4; ni++) s[ni] = (f32x4){0.f, 0.f, 0.f, 0.f};
#pragma unroll
        for (int kk = 0; kk < 64; kk += 32) {
            int co = ((((kk >> 3) + quad) ^ sl) << 3);
            bf16x8 af = *reinterpret_cast<const bf16x8*>(
                &Qs[(wave * 16 + l16) * 64 + co]);
#pragma unroll
            for (int ni = 0; ni < 4; ni++) {
                bf16x8 bf = *reinterpret_cast<const bf16x8*>(
                    &Ks[cb][(ni * 16 + l16) * 64 + co]);
                s[ni] = __builtin_amdgcn_mfma_f32_16x16x32_bf16(af, bf, s[ni], 0, 0, 0);
            }
        }

        // p = exp2(s); packed b64 Ps write at natural positions 4*l16+ni
#pragma unroll
        for (int r = 0; r < 4; r++) {
            float p0 = __builtin_amdgcn_exp2f(s[0][r]);
            float p1 = __builtin_amdgcn_exp2f(s[1][r]);
            float p2 = __builtin_amdgcn_exp2f(s[2][r]);
            float p3 = __builtin_amdgcn_exp2f(s[3][r]);
            lp[r] += (p0 + p1) + (p2 + p3);
            f32x4 pf = {p0, p1, p2, p3};
            bf16x4 pb = __builtin_convertvector(pf, bf16x4);
            int q = wave * 16 + quad * 4 + r;
            *reinterpret_cast<bf16x4*>(
                &Ps[q * 64 + (((l16 >> 1) ^ (q & 7)) << 3) + (l16 & 1) * 4]) = pb;
        }

        // O += P V (Ps rows wave-private; no barrier needed)
#pragma unroll
        for (int kk = 0; kk < 64; kk += 32) {
            int co = ((((kk >> 3) + quad) ^ sl) << 3);
            bf16x8 af = *reinterpret_cast<const bf16x8*>(
                &Ps[(wave * 16 + l16) * 64 + co]);
#pragma unroll
            for (int ni = 0; ni < 4; ni++) {
                bf16x8 bf = *reinterpret_cast<const bf16x8*>(
                    &Vt[cb][(ni * 16 + l16) * 64 + co]);
                o[ni] = __builtin_amdgcn_mfma_f32_16x16x32_bf16(af, bf, o[ni], 0, 0, 0);
            }
        }
    }

    float inv[4];
#pragma unroll
    for (int r = 0; r < 4; r++) {
        float v = lp[r];
#pragma unroll
        for (int off = 1; off < 16; off <<= 1) v += __shfl_xor(v, off);
        inv[r] = __builtin_amdgcn_rcpf(v);
    }
    // write ATT over this block's own Q-tile (cols h*64.., rows qt*64..), key s&7
#pragma unroll
    for (int ni = 0; ni < 4; ni++)
#pragma unroll
        for (int r = 0; r < 4; r++) {
            int s = qt * 64 + wave * 16 + quad * 4 + r;  // 0..2047
            int d = h * 64 + ni * 16 + l16;
            qkg[(size_t)b * 4194304 + (size_t)s * 2048 + (d ^ ((s & 7) << 3))] =
                f2bf(o[ni][r] * inv[r]);
        }
}

// ---- out-projection: ATT (QKg q-half, ld 2048) @ WoT -> f32 out ----
// 128x64 tiles, single-barrier double-buffered staging (same pipeline shape).
__global__ __launch_bounds__(256) void gemm_out(
    const u16* __restrict__ attb, const u16* __restrict__ wot,
    const float* __restrict__ bo, float* __restrict__ out) {
    __shared__ __align__(16) u16 As[2][128 * 64];
    __shared__ __align__(16) u16 Bs[2][64 * 64];

    int tid = threadIdx.x;
    int m0 = blockIdx.y * 128, n0 = blockIdx.x * 64;
    int wave = tid >> 6, lane = tid & 63;
    int wm = (wave >> 1) * 64, wn = (wave & 1) * 32;
    int l16 = lane & 15, quad = lane >> 4;
    int sl = l16 & 7;
    int rsub = lane >> 3, c16 = (lane & 7) * 8;

    f32x4 acc[4][2];
#pragma unroll
    for (int mi = 0; mi < 4; mi++)
#pragma unroll
        for (int ni = 0; ni < 2; ni++) acc[mi][ni] = (f32x4){0.f, 0.f, 0.f, 0.f};

    // prologue: stage k0=0 into buffer 0
#pragma unroll
    for (int i = 0; i < 4; i++) {
        int row = wave * 32 + i * 8 + rsub;
        dma16(&attb[(size_t)(m0 + row) * 2048 + c16], &As[0][wave * 2048 + i * 512]);
    }
#pragma unroll
    for (int i = 0; i < 2; i++) {
        int row = wave * 16 + i * 8 + rsub;
        dma16(&wot[(size_t)(n0 + row) * 1024 + c16], &Bs[0][wave * 1024 + i * 512]);
    }

    for (int it = 0; it < 16; it++) {
        __syncthreads();
        if (it < 15) {
            int nb = (it + 1) & 1, k0 = (it + 1) * 64;
#pragma unroll
            for (int i = 0; i < 4; i++) {
                int row = wave * 32 + i * 8 + rsub;
                dma16(&attb[(size_t)(m0 + row) * 2048 + k0 + c16],
                      &As[nb][wave * 2048 + i * 512]);
            }
#pragma unroll
            for (int i = 0; i < 2; i++) {
                int row = wave * 16 + i * 8 + rsub;
                dma16(&wot[(size_t)(n0 + row) * 1024 + k0 + c16],
                      &Bs[nb][wave * 1024 + i * 512]);
            }
        }
        int cb = it & 1;
#pragma unroll
        for (int kk = 0; kk < 64; kk += 32) {
            int co = ((((kk >> 3) + quad) ^ sl) << 3);
            bf16x8 af[4], bf[2];
#pragma unroll
            for (int mi = 0; mi < 4; mi++)
                af[mi] = *reinterpret_cast<const bf16x8*>(
                    &As[cb][(wm + mi * 16 + l16) * 64 + co]);
#pragma unroll
            for (int ni = 0; ni < 2; ni++)
                bf[ni] = *reinterpret_cast<const bf16x8*>(
                    &Bs[cb][(wn + ni * 16 + l16) * 64 + co]);
#pragma unroll
            for (int mi = 0; mi < 4; mi++)
#pragma unroll
                for (int ni = 0; ni < 2; ni++)
                    acc[mi][ni] = __builtin_amdgcn_mfma_f32_16x16x32_bf16(
                        af[mi], bf[ni], acc[mi][ni], 0, 0, 0);
        }
    }

#pragma unroll
    for (int ni = 0; ni < 2; ni++) {
        int n = n0 + wn + ni * 16 + l16;
        float bb = bo[n];
#pragma unroll
        for (int mi = 0; mi < 4; mi++)
#pragma unroll
            for (int r = 0; r < 4; r++)
                out[(size_t)(m0 + wm + mi * 16 + quad * 4 + r) * 1024 + n] =
                    acc[mi][ni][r] + bb;
    }
}

// ---------------- launch ----------------
extern "C" void kernel_launch(void* const* d_in, const int* in_sizes, int n_in,
                              void* d_out, int out_size, void* d_ws, size_t ws_size,
                              hipStream_t stream) {
    const float* x  = (const float*)d_in[0];
    const float* Wq = (const float*)d_in[1];
    const float* bq = (const float*)d_in[2];
    const float* Wk = (const float*)d_in[3];
    const float* bk = (const float*)d_in[4];
    const float* Wv = (const float*)d_in[5];
    const float* bv = (const float*)d_in[6];
    const float* Wo = (const float*)d_in[7];
    const float* bo = (const float*)d_in[8];

    // d_out scratch: WqT@0, WkT@2MB, WvT@4MB, WoT@6MB, xbf@8MB (all dead before
    // gemm_out's f32 write). ws: QKg[2][2048][2048]@0 (q-half becomes ATT),
    // Vgt[2048][2048]@16MB (becomes WoT park).
    u16* WT  = (u16*)d_out;
    u16* xbf = (u16*)d_out + 4 * 1048576;
    u16* QKg = (u16*)d_ws;
    u16* Vgt = (u16*)d_ws + 8 * 1048576;

    cvt_w4<<<dim3(32, 32, 4), 256, 0, stream>>>(Wq, Wk, Wv, Wo, WT);
    cvt_x<<<4096, 256, 0, stream>>>(x, xbf);

    gemm_qkv<<<dim3(24, 32), 256, 0, stream>>>(xbf, WT, bq, bk, bv, QKg, Vgt);

    attention_kern<<<dim3(32, 16, 2), 256, 0, stream>>>(QKg, Vgt);

    // park WoT in ws (Vgt dead after attention); out-projection -> f32 d_out
    hipMemcpyAsync(Vgt, WT + 3 * 1048576, (size_t)2 * 1048576,
                   hipMemcpyDeviceToDevice, stream);
    gemm_out<<<dim3(16, 32), 256, 0, stream>>>(QKg, Vgt, bo, (float*)d_out);
}